// Round 1
// baseline (137.433 us; speedup 1.0000x reference)
//
#include <hip/hip_runtime.h>
#include <stdint.h>

// Problem constants (fixed by reference: 16384x64 fp32 points, both sets)
#define N_PTS 16384
#define DIM   64
#define R_TILE 128            // rows per wave
#define C_TILE 32             // cols per MFMA tile
#define SPLITS 16             // M-dimension splits
#define CHUNK  (N_PTS / SPLITS)   // 1024 cols per wave
#define TILES  (CHUNK / C_TILE)   // 32 tiles per wave

typedef __attribute__((ext_vector_type(8)))  short bf16x8;
typedef __attribute__((ext_vector_type(16))) float f32x16;

// Order-preserving float->uint map (for atomicMin on possibly-negative floats)
__device__ __forceinline__ unsigned flipf(float f) {
    unsigned u = __float_as_uint(f);
    return u ^ (unsigned)((((int)u) >> 31) | (int)0x80000000);
}
__device__ __forceinline__ float unflipf(unsigned k) {
    unsigned u = (k & 0x80000000u) ? (k ^ 0x80000000u) : ~k;
    return __uint_as_float(u);
}

__device__ __forceinline__ unsigned short f2bf(float f) {
    unsigned u = __float_as_uint(f);
    u += 0x7FFFu + ((u >> 16) & 1u);   // RNE
    return (unsigned short)(u >> 16);
}

// Prepass: a_sq/b_sq in fp32, bf16 copies (A scaled by -2 so MFMA directly
// yields  b_sq - 2*a.b  when accumulator is seeded with b_sq), init minkeys.
__global__ __launch_bounds__(256) void prep_kernel(
        const float* __restrict__ from_pts, const float* __restrict__ to_pts,
        unsigned* __restrict__ minkeys, float* __restrict__ a_sq,
        float* __restrict__ b_sq, unsigned short* __restrict__ Abf,
        unsigned short* __restrict__ Bbf) {
    int t = blockIdx.x * 256 + threadIdx.x;        // 0 .. 32767
    bool isA = t < N_PTS;
    int r = t & (N_PTS - 1);
    const float4* row = (const float4*)((isA ? from_pts : to_pts) + (size_t)r * DIM);
    float scale = isA ? -2.0f : 1.0f;
    unsigned short out[DIM];
    float s = 0.0f;
    #pragma unroll
    for (int i = 0; i < DIM / 4; i++) {
        float4 v = row[i];
        s += v.x * v.x + v.y * v.y + v.z * v.z + v.w * v.w;
        out[4 * i + 0] = f2bf(v.x * scale);
        out[4 * i + 1] = f2bf(v.y * scale);
        out[4 * i + 2] = f2bf(v.z * scale);
        out[4 * i + 3] = f2bf(v.w * scale);
    }
    uint4* dst = (uint4*)((isA ? Abf : Bbf) + (size_t)r * DIM);
    const uint4* src = (const uint4*)out;
    #pragma unroll
    for (int j = 0; j < 8; j++) dst[j] = src[j];
    if (isA) { a_sq[r] = s; minkeys[r] = 0xFFFFFFFFu; }
    else     { b_sq[r] = s; }
}

// Main: each wave computes running row-min of (b_sq[c] - 2*a.b) over its
// 128-row x 1024-col slab.  A fragments live in registers for the whole
// kernel; B fragments load straight from L2 (B bf16 = 2 MB, L2-resident).
// No LDS, no __syncthreads in the hot loop.
__global__ __launch_bounds__(256, 2) void main_kernel(
        const unsigned short* __restrict__ Abf,
        const unsigned short* __restrict__ Bbf,
        const float* __restrict__ b_sq, unsigned* __restrict__ minkeys) {
    const int lane = threadIdx.x & 63;
    const int wid  = (blockIdx.x << 2) + (threadIdx.x >> 6);   // 0..2047
    const int rg   = wid & 127;        // row-group
    const int sp   = wid >> 7;         // split
    const int row_base = rg * R_TILE;
    const int col_base = sp * CHUNK;
    const int l31 = lane & 31;
    const int h   = lane >> 5;         // 0/1

    // A fragments: A[m=lane&31][k=8*(lane>>5)+j], 4 row-subtiles x 4 k-blocks
    bf16x8 Af[4][4];
    #pragma unroll
    for (int i = 0; i < 4; i++) {
        const unsigned short* arow = Abf + (size_t)(row_base + i * 32 + l31) * DIM;
        #pragma unroll
        for (int kb = 0; kb < 4; kb++)
            Af[i][kb] = *(const bf16x8*)(arow + kb * 16 + h * 8);
    }

    float rmin[4][16];
    #pragma unroll
    for (int i = 0; i < 4; i++)
        #pragma unroll
        for (int r = 0; r < 16; r++) rmin[i][r] = 3.0e38f;

    for (int t = 0; t < TILES; t++) {
        const int col0 = col_base + t * C_TILE;
        const unsigned short* brow = Bbf + (size_t)(col0 + l31) * DIM;
        bf16x8 Bf[4];
        #pragma unroll
        for (int kb = 0; kb < 4; kb++)
            Bf[kb] = *(const bf16x8*)(brow + kb * 16 + h * 8);
        float bsq = b_sq[col0 + l31];
        f32x16 cinit;
        #pragma unroll
        for (int r = 0; r < 16; r++) cinit[r] = bsq;   // C col = lane&31
        #pragma unroll
        for (int i = 0; i < 4; i++) {
            f32x16 acc = __builtin_amdgcn_mfma_f32_32x32x16_bf16(Af[i][0], Bf[0], cinit, 0, 0, 0);
            #pragma unroll
            for (int kb = 1; kb < 4; kb++)
                acc = __builtin_amdgcn_mfma_f32_32x32x16_bf16(Af[i][kb], Bf[kb], acc, 0, 0, 0);
            #pragma unroll
            for (int r = 0; r < 16; r++)
                rmin[i][r] = fminf(rmin[i][r], acc[r]);   // acc = b_sq - 2*a.b
        }
    }

    // Cross-lane min over the 32-lane half that shares each row, then one
    // device-scope atomicMin per row (2 lanes active per predicated atomic).
    #pragma unroll
    for (int i = 0; i < 4; i++) {
        #pragma unroll
        for (int r = 0; r < 16; r++) {
            float v = rmin[i][r];
            v = fminf(v, __shfl_xor(v, 1));
            v = fminf(v, __shfl_xor(v, 2));
            v = fminf(v, __shfl_xor(v, 4));
            v = fminf(v, __shfl_xor(v, 8));
            v = fminf(v, __shfl_xor(v, 16));
            int row = row_base + i * 32 + (r & 3) + 8 * (r >> 2) + 4 * h;
            if (l31 == ((i * 16 + r) & 31))
                atomicMin(minkeys + row, flipf(v));
        }
    }
}

// Final: sum over rows of a_sq[r] + min(b_sq - 2ab) -> scalar
__global__ __launch_bounds__(256) void finish_kernel(
        const float* __restrict__ a_sq, const unsigned* __restrict__ minkeys,
        float* __restrict__ out) {
    __shared__ float red[4];
    float s = 0.0f;
    for (int r = threadIdx.x; r < N_PTS; r += 256)
        s += a_sq[r] + unflipf(minkeys[r]);
    #pragma unroll
    for (int m = 1; m < 64; m <<= 1) s += __shfl_xor(s, m);
    if ((threadIdx.x & 63) == 0) red[threadIdx.x >> 6] = s;
    __syncthreads();
    if (threadIdx.x == 0) out[0] = red[0] + red[1] + red[2] + red[3];
}

extern "C" void kernel_launch(void* const* d_in, const int* in_sizes, int n_in,
                              void* d_out, int out_size, void* d_ws, size_t ws_size,
                              hipStream_t stream) {
    const float* from_pts = (const float*)d_in[0];
    const float* to_pts   = (const float*)d_in[1];
    char* ws = (char*)d_ws;
    unsigned*       minkeys = (unsigned*)ws;                                   //  64 KB
    float*          a_sq    = (float*)(ws + (64 << 10));                       //  64 KB
    float*          b_sq    = (float*)(ws + (128 << 10));                      //  64 KB
    unsigned short* Abf     = (unsigned short*)(ws + (192 << 10));             //   2 MB
    unsigned short* Bbf     = (unsigned short*)(ws + (192 << 10) + (2 << 20)); //   2 MB

    prep_kernel<<<(2 * N_PTS) / 256, 256, 0, stream>>>(from_pts, to_pts, minkeys,
                                                       a_sq, b_sq, Abf, Bbf);
    main_kernel<<<(N_PTS / R_TILE) * SPLITS / 4, 256, 0, stream>>>(Abf, Bbf, b_sq, minkeys);
    finish_kernel<<<1, 256, 0, stream>>>(a_sq, minkeys, (float*)d_out);
}

// Round 3
// 132.293 us; speedup vs baseline: 1.0389x; 1.0389x over previous
//
#include <hip/hip_runtime.h>
#include <stdint.h>

// Problem constants (fixed by reference: 16384x64 fp32 points, both sets)
#define N_PTS 16384
#define DIM   64
#define R_TILE 64             // rows per wave (2 x 32-row MFMA subtiles)
#define C_TILE 32             // cols per MFMA tile
#define SPLITS 16             // M-dimension splits
#define CHUNK  (N_PTS / SPLITS)   // 1024 cols per wave
#define TILES  (CHUNK / C_TILE)   // 32 tiles per wave
#define RGROUPS (N_PTS / R_TILE)  // 256 row-groups

typedef __attribute__((ext_vector_type(8)))  short bf16x8;
typedef __attribute__((ext_vector_type(16))) float f32x16;

// Order-preserving float->uint map (for atomicMin on possibly-negative floats)
__device__ __forceinline__ unsigned flipf(float f) {
    unsigned u = __float_as_uint(f);
    return u ^ (unsigned)((((int)u) >> 31) | (int)0x80000000);
}
__device__ __forceinline__ float unflipf(unsigned k) {
    unsigned u = (k & 0x80000000u) ? (k ^ 0x80000000u) : ~k;
    return __uint_as_float(u);
}

__device__ __forceinline__ unsigned short f2bf(float f) {
    unsigned u = __float_as_uint(f);
    u += 0x7FFFu + ((u >> 16) & 1u);   // RNE
    return (unsigned short)(u >> 16);
}

// Prepass (coalesced): thread i owns float4 element i of A then B.
// 16 consecutive lanes cover one row -> segmented shuffle reduction for
// a_sq/b_sq. Writes bf16 (A scaled by -2), inits minkeys, zeroes d_out.
// GRID MUST BE 2*N_PTS*(DIM/4)/256 = 2048 blocks (one thread per float4!)
__global__ __launch_bounds__(256) void prep_kernel(
        const float* __restrict__ from_pts, const float* __restrict__ to_pts,
        unsigned* __restrict__ minkeys, float* __restrict__ a_sq,
        float* __restrict__ b_sq, unsigned short* __restrict__ Abf,
        unsigned short* __restrict__ Bbf, float* __restrict__ out) {
    int gid = blockIdx.x * 256 + threadIdx.x;        // 0 .. 2*16384*16-1
    bool isA = gid < N_PTS * (DIM / 4);
    int i = gid & (N_PTS * (DIM / 4) - 1);           // float4 index
    int row = i >> 4;                                 // 16 float4 per row
    int q   = i & 15;
    float4 v = ((const float4*)(isA ? from_pts : to_pts))[i];
    float s = v.x * v.x + v.y * v.y + v.z * v.z + v.w * v.w;
    // segmented reduce over the 16 lanes sharing this row
    s += __shfl_xor(s, 1); s += __shfl_xor(s, 2);
    s += __shfl_xor(s, 4); s += __shfl_xor(s, 8);
    float scale = isA ? -2.0f : 1.0f;
    ushort4 w;
    w.x = f2bf(v.x * scale); w.y = f2bf(v.y * scale);
    w.z = f2bf(v.z * scale); w.w = f2bf(v.w * scale);
    ((ushort4*)(isA ? Abf : Bbf))[i] = w;
    if (q == 0) {
        if (isA) { a_sq[row] = s; minkeys[row] = 0xFFFFFFFFu; }
        else     { b_sq[row] = s; }
    }
    if (gid == 0) out[0] = 0.0f;
}

// Main: each wave owns a 64-row x 1024-col slab, computing the running
// row-min of (b_sq[c] - 2*a.b).  A fragments stay in registers; B fragments
// are prefetched one tile ahead straight from L2 (B bf16 = 2 MB, resident).
// No LDS, no barriers. ~124 regs/wave -> 4 waves/SIMD at 1024 blocks (4/CU).
__global__ __launch_bounds__(256, 4) void main_kernel(
        const unsigned short* __restrict__ Abf,
        const unsigned short* __restrict__ Bbf,
        const float* __restrict__ b_sq, unsigned* __restrict__ minkeys) {
    const int lane = threadIdx.x & 63;
    const int wid  = (blockIdx.x << 2) + (threadIdx.x >> 6);   // 0..4095
    const int rg   = wid & (RGROUPS - 1);    // row-group (block's 4 waves:
    const int sp   = wid >> 8;               //  consecutive rg, same split)
    const int row_base = rg * R_TILE;
    const int col_base = sp * CHUNK;
    const int l31 = lane & 31;
    const int h   = lane >> 5;               // 0/1 = K-half

    // A fragments: A[m=lane&31][k=8*h+j], 2 row-subtiles x 4 k-blocks
    bf16x8 Af[2][4];
    #pragma unroll
    for (int i = 0; i < 2; i++) {
        const unsigned short* arow = Abf + (size_t)(row_base + i * 32 + l31) * DIM + h * 8;
        #pragma unroll
        for (int kb = 0; kb < 4; kb++)
            Af[i][kb] = *(const bf16x8*)(arow + kb * 16);
    }

    float rmin[2][16];
    #pragma unroll
    for (int i = 0; i < 2; i++)
        #pragma unroll
        for (int r = 0; r < 16; r++) rmin[i][r] = 3.0e38f;

    const unsigned short* bptr = Bbf + (size_t)(col_base + l31) * DIM + h * 8;
    const float* bsqp = b_sq + col_base + l31;

    bf16x8 Bc[4], Bn[4];
    float bsqc, bsqn;
    #pragma unroll
    for (int kb = 0; kb < 4; kb++) Bc[kb] = *(const bf16x8*)(bptr + kb * 16);
    bsqc = *bsqp;

    for (int t = 0; t < TILES; t++) {
        // prefetch tile t+1 (clamped re-read of last tile: harmless L1 hit)
        int tn = (t + 1 < TILES) ? (t + 1) : t;
        const unsigned short* nb = bptr + (size_t)tn * C_TILE * DIM;
        #pragma unroll
        for (int kb = 0; kb < 4; kb++) Bn[kb] = *(const bf16x8*)(nb + kb * 16);
        bsqn = bsqp[tn * C_TILE];

        f32x16 cinit;
        #pragma unroll
        for (int r = 0; r < 16; r++) cinit[r] = bsqc;   // C col = lane&31
        #pragma unroll
        for (int i = 0; i < 2; i++) {
            f32x16 acc = __builtin_amdgcn_mfma_f32_32x32x16_bf16(Af[i][0], Bc[0], cinit, 0, 0, 0);
            #pragma unroll
            for (int kb = 1; kb < 4; kb++)
                acc = __builtin_amdgcn_mfma_f32_32x32x16_bf16(Af[i][kb], Bc[kb], acc, 0, 0, 0);
            #pragma unroll
            for (int r = 0; r < 16; r++)
                rmin[i][r] = fminf(rmin[i][r], acc[r]);   // acc = b_sq - 2*a.b
        }
        #pragma unroll
        for (int kb = 0; kb < 4; kb++) Bc[kb] = Bn[kb];
        bsqc = bsqn;
    }

    // Cross-lane min over the 32 lanes sharing each output row, then one
    // device-scope atomicMin per row (one (i,r) pair per lane slot).
    #pragma unroll
    for (int i = 0; i < 2; i++) {
        #pragma unroll
        for (int r = 0; r < 16; r++) {
            float v = rmin[i][r];
            v = fminf(v, __shfl_xor(v, 1));
            v = fminf(v, __shfl_xor(v, 2));
            v = fminf(v, __shfl_xor(v, 4));
            v = fminf(v, __shfl_xor(v, 8));
            v = fminf(v, __shfl_xor(v, 16));
            int row = row_base + i * 32 + (r & 3) + 8 * (r >> 2) + 4 * h;
            if (l31 == ((i * 16 + r) & 31))
                atomicMin(minkeys + row, flipf(v));
        }
    }
}

// Final: sum over rows of a_sq[r] + min_c(b_sq[c] - 2 a.b) -> scalar.
// 64 blocks x 256 threads = exactly one row per thread; atomicAdd partials.
__global__ __launch_bounds__(256) void finish_kernel(
        const float* __restrict__ a_sq, const unsigned* __restrict__ minkeys,
        float* __restrict__ out) {
    __shared__ float red[4];
    int r = blockIdx.x * 256 + threadIdx.x;
    float s = a_sq[r] + unflipf(minkeys[r]);
    #pragma unroll
    for (int m = 1; m < 64; m <<= 1) s += __shfl_xor(s, m);
    if ((threadIdx.x & 63) == 0) red[threadIdx.x >> 6] = s;
    __syncthreads();
    if (threadIdx.x == 0)
        atomicAdd(out, red[0] + red[1] + red[2] + red[3]);
}

extern "C" void kernel_launch(void* const* d_in, const int* in_sizes, int n_in,
                              void* d_out, int out_size, void* d_ws, size_t ws_size,
                              hipStream_t stream) {
    const float* from_pts = (const float*)d_in[0];
    const float* to_pts   = (const float*)d_in[1];
    char* ws = (char*)d_ws;
    unsigned*       minkeys = (unsigned*)ws;                                   //  64 KB
    float*          a_sq    = (float*)(ws + (64 << 10));                       //  64 KB
    float*          b_sq    = (float*)(ws + (128 << 10));                      //  64 KB
    unsigned short* Abf     = (unsigned short*)(ws + (192 << 10));             //   2 MB
    unsigned short* Bbf     = (unsigned short*)(ws + (192 << 10) + (2 << 20)); //   2 MB

    // one thread per float4 across both inputs: 2*16384*16/256 = 2048 blocks
    prep_kernel<<<(2 * N_PTS * (DIM / 4)) / 256, 256, 0, stream>>>(
        from_pts, to_pts, minkeys, a_sq, b_sq, Abf, Bbf, (float*)d_out);
    main_kernel<<<RGROUPS * SPLITS / 4, 256, 0, stream>>>(Abf, Bbf, b_sq, minkeys);
    finish_kernel<<<N_PTS / 256, 256, 0, stream>>>(a_sq, minkeys, (float*)d_out);
}